// Round 16
// baseline (288.325 us; speedup 1.0000x reference)
//
#include <hip/hip_runtime.h>
#include <hip/hip_bf16.h>

#define H 2048
#define NH 32
#define HD 64
#define BB 2
#define SS 2048
#define MM (BB*SS)   // 4096 rows

typedef __attribute__((ext_vector_type(8))) short bf16x8;
typedef __attribute__((ext_vector_type(4))) float f32x4;
typedef __attribute__((ext_vector_type(16))) float f32x16;
typedef unsigned short u16;
typedef unsigned int u32;
typedef __attribute__((ext_vector_type(4))) u32 u32x4;

#define MFMA16(acc, av, bv) acc = __builtin_amdgcn_mfma_f32_16x16x32_bf16(av, bv, acc, 0, 0, 0)

static __device__ __forceinline__ u16 f2bf(float f){
  union { float f; u32 i; } v; v.f = f;
  u32 x = v.i;
  return (u16)((x + 0x7FFFu + ((x >> 16) & 1u)) >> 16);  // RNE
}
static __device__ __forceinline__ float bf2f(u16 u){
  union { u32 i; float f; } v; v.i = ((u32)u) << 16; return v.f;
}
// packed f32x2 -> bf16x2 (low = a, high = b), single HW instr
static __device__ __forceinline__ u32 pk2(float a, float b){
  u32 r;
  asm("v_cvt_pk_bf16_f32 %0, %1, %2" : "=v"(r) : "v"(a), "v"(b));
  return r;
}

static __device__ __forceinline__ void gload16(const u16* g, u16* l){
  __builtin_amdgcn_global_load_lds((const __attribute__((address_space(1))) void*)g,
                                   (__attribute__((address_space(3))) void*)l, 16, 0, 0);
}

// ---------------- 1. X f32 -> bf16 ----------------
__global__ void k_cvt(const float* __restrict__ src, u16* __restrict__ dst){
  const int i = (blockIdx.x * 256 + threadIdx.x) * 4;
  float4 v = *(const float4*)(src + i);
  ushort4 o;
  o.x = f2bf(v.x); o.y = f2bf(v.y); o.z = f2bf(v.z); o.w = f2bf(v.w);
  *(ushort4*)(dst + i) = o;
}

// ---------------- 2. W [K][N] f32 -> Wt [N][K] bf16 ----------------
__global__ void k_wtrans(const float* __restrict__ w0, const float* __restrict__ w1,
                         const float* __restrict__ w2, const float* __restrict__ w3,
                         u16* __restrict__ d0, u16* __restrict__ d1,
                         u16* __restrict__ d2, u16* __restrict__ d3){
  __shared__ float tile[32][33];
  const int z = blockIdx.z;
  const float* w = z==0 ? w0 : z==1 ? w1 : z==2 ? w2 : w3;
  u16* d        = z==0 ? d0 : z==1 ? d1 : z==2 ? d2 : d3;
  const int n0 = blockIdx.x * 32, k0 = blockIdx.y * 32;
  const int tx = threadIdx.x, ty = threadIdx.y;  // 32 x 8
  #pragma unroll
  for (int j = 0; j < 4; j++)
    tile[ty + 8*j][tx] = w[(size_t)(k0 + ty + 8*j) * H + n0 + tx];
  __syncthreads();
  #pragma unroll
  for (int j = 0; j < 4; j++)
    d[(size_t)(n0 + ty + 8*j) * H + k0 + tx] = f2bf(tile[tx][ty + 8*j]);
}

// ---------------- 3. QKV GEMM, flattened N=6144 (2 blocks/CU; A-resident swizzle) ----------------
// BM=128 x BN=192 -> LDS 80 KiB -> 2 blocks/CU. Grid 32x32 = 1024 blocks.
// XCD swizzle SWAPPED vs r13: each XCD owns 4 gx (A-share 2MB -> L2-resident)
// and iterates all 32 gy (B 25MB streamed from L3). r13's orientation re-fetched
// the full A per XCD (FETCH 212MB vs 42MB unique).
__global__ __launch_bounds__(512, 4) void k_gemm8(
    const u16* __restrict__ A, const u16* __restrict__ Bt,
    u16* __restrict__ CQ, u16* __restrict__ CK, u16* __restrict__ CV,
    int M, int K){
  __shared__ __align__(16) u16 As[2][128][64];
  __shared__ __align__(16) u16 Bs[2][192][64];
  const int flat = blockIdx.x;                  // 1024 blocks
  const int id = (flat & 7) * 128 + (flat >> 3);
  const int gx = id >> 5, gy = id & 31;         // per XCD: gx in [4x,4x+4), all gy
  const int m0 = gx * 128, n0 = gy * 192;
  const int t = threadIdx.x, w = t >> 6, l = t & 63;
  const int wm = w >> 2, wn = w & 3;            // wave rows wm*64.., cols wn*48..
  const int lrow = l & 15, lk = (l >> 4) * 8;
  const int sw = (lrow & 7) * 8;                // read-side swizzle
  const int sr = t >> 3, sc = (t & 7) * 8;      // staging lane pattern
  const int ssc = sc ^ ((sr & 7) * 8);          // pre-swizzled global col
  const int NK = K >> 6;

  auto stageA = [&](int kt, int u){
    const size_t kb = (size_t)kt * 64 + ssc;
    #pragma unroll
    for (int c = 0; c < 2; c++)
      gload16(A + (size_t)(m0 + c*64 + sr) * K + kb, &As[u][c*64 + sr][sc]);
  };
  auto stageB = [&](int kt, int u){
    const size_t kb = (size_t)kt * 64 + ssc;
    #pragma unroll
    for (int c = 0; c < 3; c++)
      gload16(Bt + (size_t)(n0 + c*64 + sr) * K + kb, &Bs[u][c*64 + sr][sc]);
  };

  f32x4 acc[4][3] = {};

  stageA(0, 0); stageB(0, 0);
  stageA(1, 1); stageB(1, 1);
  asm volatile("s_waitcnt vmcnt(5)" ::: "memory");
  __builtin_amdgcn_s_barrier();

  #pragma unroll 1
  for (int kt = 0; kt < NK; ++kt){
    const int u = kt & 1;
    const bool more = (kt + 2 < NK);
    bf16x8 b0[3], b1[3], a0, a1;

    // ---- phase 0: B kh0 + A mb{0,1} kh0 -> 6 MFMA ----
    #pragma unroll
    for (int n = 0; n < 3; n++)
      b0[n] = *(const bf16x8*)&Bs[u][wn*48 + n*16 + lrow][lk ^ sw];
    a0 = *(const bf16x8*)&As[u][wm*64 +  0 + lrow][lk ^ sw];
    a1 = *(const bf16x8*)&As[u][wm*64 + 16 + lrow][lk ^ sw];
    __builtin_amdgcn_s_setprio(1);
    #pragma unroll
    for (int n = 0; n < 3; n++){
      MFMA16(acc[0][n], a0, b0[n]);
      MFMA16(acc[1][n], a1, b0[n]);
    }
    __builtin_amdgcn_s_setprio(0);
    __builtin_amdgcn_s_barrier();

    // ---- phase 1: B kh1 + A mb{0,1} kh1 -> 6 MFMA  [B slot fully consumed] ----
    #pragma unroll
    for (int n = 0; n < 3; n++)
      b1[n] = *(const bf16x8*)&Bs[u][wn*48 + n*16 + lrow][(32 + lk) ^ sw];
    a0 = *(const bf16x8*)&As[u][wm*64 +  0 + lrow][(32 + lk) ^ sw];
    a1 = *(const bf16x8*)&As[u][wm*64 + 16 + lrow][(32 + lk) ^ sw];
    __builtin_amdgcn_s_setprio(1);
    #pragma unroll
    for (int n = 0; n < 3; n++){
      MFMA16(acc[0][n], a0, b1[n]);
      MFMA16(acc[1][n], a1, b1[n]);
    }
    __builtin_amdgcn_s_setprio(0);
    __builtin_amdgcn_s_barrier();

    // ---- phase 2: stage B(kt+2) into freed B slot; A mb{2,3} kh0 -> 6 MFMA ----
    if (more) stageB(kt + 2, u);
    a0 = *(const bf16x8*)&As[u][wm*64 + 32 + lrow][lk ^ sw];
    a1 = *(const bf16x8*)&As[u][wm*64 + 48 + lrow][lk ^ sw];
    __builtin_amdgcn_s_setprio(1);
    #pragma unroll
    for (int n = 0; n < 3; n++){
      MFMA16(acc[2][n], a0, b0[n]);
      MFMA16(acc[3][n], a1, b0[n]);
    }
    __builtin_amdgcn_s_setprio(0);
    __builtin_amdgcn_s_barrier();

    // ---- phase 3: A mb{2,3} kh1 -> 6 MFMA ----
    a0 = *(const bf16x8*)&As[u][wm*64 + 32 + lrow][(32 + lk) ^ sw];
    a1 = *(const bf16x8*)&As[u][wm*64 + 48 + lrow][(32 + lk) ^ sw];
    __builtin_amdgcn_s_setprio(1);
    #pragma unroll
    for (int n = 0; n < 3; n++){
      MFMA16(acc[2][n], a0, b1[n]);
      MFMA16(acc[3][n], a1, b1[n]);
    }
    __builtin_amdgcn_s_setprio(0);
    __builtin_amdgcn_s_barrier();   // A slot fully consumed

    if (more){
      stageA(kt + 2, u);
      asm volatile("s_waitcnt vmcnt(5)" ::: "memory");   // kt+1 landed; kt+2's 5 in flight
      __builtin_amdgcn_s_barrier();
    } else if (kt + 1 < NK){
      asm volatile("s_waitcnt vmcnt(0)" ::: "memory");
      __builtin_amdgcn_s_barrier();
    }
  }

  #pragma unroll
  for (int m = 0; m < 4; m++)
    #pragma unroll
    for (int n = 0; n < 3; n++){
      const int ncol = n0 + wn*48 + n*16 + lrow;
      const int z = ncol >> 11;
      u16* C = (z == 0 ? CQ : z == 1 ? CK : CV) + (ncol & 2047);
      #pragma unroll
      for (int r = 0; r < 4; r++){
        const int row = m0 + wm*64 + m*16 + (l >> 4)*4 + r;
        C[(size_t)row * H] = f2bf(acc[m][n][r]);
      }
    }
}

// ---------------- 3b. out-proj GEMM: C[4096][2048] f32 = A * Wot^T ----------------
// BM=128 x BN=128 -> LDS 64 KiB -> 2 blocks/CU. Grid 32x16 = 512 blocks.
// A-resident XCD swizzle (per XCD: gx in [4x,4x+4), all gy).
__global__ __launch_bounds__(512, 4) void k_gemmo(
    const u16* __restrict__ A, const u16* __restrict__ Bt,
    float* __restrict__ C, int M, int N, int K){
  __shared__ __align__(16) u16 As[2][128][64];
  __shared__ __align__(16) u16 Bs[2][128][64];
  const int flat = blockIdx.x;                 // 512 blocks
  const int id = (flat & 7) * 64 + (flat >> 3);
  const int gx = id >> 4, gy = id & 15;        // per XCD: gx in [4x,4x+4), all gy
  const int m0 = gx * 128, n0 = gy * 128;
  const int t = threadIdx.x, w = t >> 6, l = t & 63;
  const int wm = w >> 2, wn = w & 3;           // wave rows wm*64.., cols wn*32..
  const int lrow = l & 15, lk = (l >> 4) * 8;
  const int sw = (lrow & 7) * 8;
  const int sr = t >> 3, sc = (t & 7) * 8;
  const int ssc = sc ^ ((sr & 7) * 8);
  const int NK = K >> 6;

  auto stageA = [&](int kt, int u){
    const size_t kb = (size_t)kt * 64 + ssc;
    #pragma unroll
    for (int c = 0; c < 2; c++)
      gload16(A + (size_t)(m0 + c*64 + sr) * K + kb, &As[u][c*64 + sr][sc]);
  };
  auto stageB = [&](int kt, int u){
    const size_t kb = (size_t)kt * 64 + ssc;
    #pragma unroll
    for (int c = 0; c < 2; c++)
      gload16(Bt + (size_t)(n0 + c*64 + sr) * K + kb, &Bs[u][c*64 + sr][sc]);
  };

  f32x4 acc[4][2] = {};

  stageA(0, 0); stageB(0, 0);
  stageA(1, 1); stageB(1, 1);
  asm volatile("s_waitcnt vmcnt(4)" ::: "memory");
  __builtin_amdgcn_s_barrier();

  #pragma unroll 1
  for (int kt = 0; kt < NK; ++kt){
    const int u = kt & 1;
    const bool more = (kt + 2 < NK);
    bf16x8 b0[2], b1[2], a0, a1;

    // p0: B kh0 + A mb{0,1} kh0 -> 4 MFMA
    #pragma unroll
    for (int n = 0; n < 2; n++)
      b0[n] = *(const bf16x8*)&Bs[u][wn*32 + n*16 + lrow][lk ^ sw];
    a0 = *(const bf16x8*)&As[u][wm*64 +  0 + lrow][lk ^ sw];
    a1 = *(const bf16x8*)&As[u][wm*64 + 16 + lrow][lk ^ sw];
    __builtin_amdgcn_s_setprio(1);
    #pragma unroll
    for (int n = 0; n < 2; n++){
      MFMA16(acc[0][n], a0, b0[n]);
      MFMA16(acc[1][n], a1, b0[n]);
    }
    __builtin_amdgcn_s_setprio(0);
    __builtin_amdgcn_s_barrier();

    // p1: B kh1 + A mb{0,1} kh1 -> 4 MFMA  [B slot consumed]
    #pragma unroll
    for (int n = 0; n < 2; n++)
      b1[n] = *(const bf16x8*)&Bs[u][wn*32 + n*16 + lrow][(32 + lk) ^ sw];
    a0 = *(const bf16x8*)&As[u][wm*64 +  0 + lrow][(32 + lk) ^ sw];
    a1 = *(const bf16x8*)&As[u][wm*64 + 16 + lrow][(32 + lk) ^ sw];
    __builtin_amdgcn_s_setprio(1);
    #pragma unroll
    for (int n = 0; n < 2; n++){
      MFMA16(acc[0][n], a0, b1[n]);
      MFMA16(acc[1][n], a1, b1[n]);
    }
    __builtin_amdgcn_s_setprio(0);
    __builtin_amdgcn_s_barrier();

    // p2: stage B(kt+2); A mb{2,3} kh0 -> 4 MFMA
    if (more) stageB(kt + 2, u);
    a0 = *(const bf16x8*)&As[u][wm*64 + 32 + lrow][lk ^ sw];
    a1 = *(const bf16x8*)&As[u][wm*64 + 48 + lrow][lk ^ sw];
    __builtin_amdgcn_s_setprio(1);
    #pragma unroll
    for (int n = 0; n < 2; n++){
      MFMA16(acc[2][n], a0, b0[n]);
      MFMA16(acc[3][n], a1, b0[n]);
    }
    __builtin_amdgcn_s_setprio(0);
    __builtin_amdgcn_s_barrier();

    // p3: A mb{2,3} kh1 -> 4 MFMA
    a0 = *(const bf16x8*)&As[u][wm*64 + 32 + lrow][(32 + lk) ^ sw];
    a1 = *(const bf16x8*)&As[u][wm*64 + 48 + lrow][(32 + lk) ^ sw];
    __builtin_amdgcn_s_setprio(1);
    #pragma unroll
    for (int n = 0; n < 2; n++){
      MFMA16(acc[2][n], a0, b1[n]);
      MFMA16(acc[3][n], a1, b1[n]);
    }
    __builtin_amdgcn_s_setprio(0);
    __builtin_amdgcn_s_barrier();

    if (more){
      stageA(kt + 2, u);
      asm volatile("s_waitcnt vmcnt(4)" ::: "memory");
      __builtin_amdgcn_s_barrier();
    } else if (kt + 1 < NK){
      asm volatile("s_waitcnt vmcnt(0)" ::: "memory");
      __builtin_amdgcn_s_barrier();
    }
  }

  #pragma unroll
  for (int m = 0; m < 4; m++)
    #pragma unroll
    for (int n = 0; n < 2; n++){
      const int col = n0 + wn*32 + n*16 + lrow;
      #pragma unroll
      for (int r = 0; r < 4; r++){
        const int row = m0 + wm*64 + m*16 + (l >> 4)*4 + r;
        C[(size_t)row * N + col] = acc[m][n][r];
      }
    }
}

// ---------------- 4. RoPE on K only, in place (Q-RoPE fused into k_attn) ----------------
__global__ void k_rope(u16* __restrict__ Kp){
  const int idx = blockIdx.x * 256 + threadIdx.x;  // 4096*32*4 threads
  const int quad = idx & 3;
  const int h = (idx >> 2) & 31;
  const int row = idx >> 7;
  const int s = row & (SS - 1);
  const int i0 = quad * 8;
  u16* k = Kp + (size_t)row * H + h * HD;
  uint4 k1v = *(const uint4*)(k + i0);
  uint4 k2v = *(const uint4*)(k + i0 + 32);
  u16* k1 = (u16*)&k1v; u16* k2 = (u16*)&k2v;
  const float sf = (float)s;
  #pragma unroll
  for (int e = 0; e < 8; e++){
    const int i = i0 + e;
    const float inv = exp2f(-0.4152410118609203f * (float)i);  // 10000^(-i/32)
    float rev = sf * inv * 0.15915494309189535f;               // radians -> revolutions
    rev -= floorf(rev);
    const float sn = __builtin_amdgcn_sinf(rev);
    const float cs = __builtin_amdgcn_cosf(rev);
    const float ka = bf2f(k1[e]), kb = bf2f(k2[e]);
    k1[e] = f2bf(ka*cs - kb*sn);
    k2[e] = f2bf(kb*cs + ka*sn);
  }
  *(uint4*)(k + i0)      = k1v;
  *(uint4*)(k + i0 + 32) = k2v;
}

// ---------------- 5. causal flash attention (r14 version, measured best) ----------------
// block = 256 thr (4 waves x 32 q-rows), grid 8x64 = 512 blocks (2/CU).
// Block x handles q-tiles {15-x, x} -> uniform 36 KV-iterations.
// 2-tile unrolled pipeline: Ks[4]/Vs[4]; per 2 tiles: stage t+2,t+3, compute
// both, one vmcnt(0)+publish+barrier. + defer-max (THR=11.5 exp2-domain)
// + deferred sum-shfl.
__global__ __launch_bounds__(256, 2) void k_attn(
    const u16* __restrict__ Q, const u16* __restrict__ K,
    const u16* __restrict__ V, u16* __restrict__ O){
  __shared__ __align__(16) u16 Ks[4][64][64];   // swizzled: col ^ (row&7)*8
  __shared__ __align__(16) u16 Vs[4][64][72];   // transposed Vs[d][j], j ^ (d>>3)*8
  const int t = threadIdx.x, w = t >> 6, l = t & 63;
  const int x = blockIdx.x, bh = blockIdx.y;
  const int b = bh >> 5, h = bh & 31;
  const u16* kp = K + (size_t)(b*SS) * H + h * HD;
  const u16* vp = V + (size_t)(b*SS) * H + h * HD;
  const int sr = t >> 3, sc = (t & 7) * 8;      // staging: linear-LDS pattern
  const int ssc = sc ^ ((sr & 7) * 8);          // pre-swizzled global col for K
  const int hi = l >> 5, lq = l & 31;
  const float QSC = 0.18033688011112042f;       // (1/8) * log2(e)

  auto stageK = [&](int tile, int buf){
    const int jb = tile * 64;
    gload16(kp + (size_t)(jb + sr) * H + ssc,      &Ks[buf][sr][sc]);
    gload16(kp + (size_t)(jb + 32 + sr) * H + ssc, &Ks[buf][32 + sr][sc]);
  };
  auto loadV = [&](int tile, uint4* vv){
    const int jb = tile * 64;
    vv[0] = *(const uint4*)(vp + (size_t)(jb + sr) * H + sc);
    vv[1] = *(const uint4*)(vp + (size_t)(jb + 32 + sr) * H + sc);
  };
  auto publishV = [&](const uint4* vv, int buf){
    #pragma unroll
    for (int c = 0; c < 2; c++){
      const int j = c*32 + sr;
      const u16* pv = (const u16*)&vv[c];
      #pragma unroll
      for (int e = 0; e < 8; e++){
        const int d = sc + e;
        Vs[buf][d][j ^ ((d >> 3) * 8)] = pv[e];
      }
    }
  };

  #pragma unroll 1
  for (int pp = 0; pp < 2; pp++){
    const int qt = pp ? x : (15 - x);           // heavy pass first
    const int NT = 2*qt + 2;                    // even
    const int qw0 = qt*128 + w*32;
    const int qrow = qw0 + lq;                  // this lane's q index (= seq pos)

    // ---- Q fragments: load raw, apply RoPE + QSC in-register ----
    const u16* qptr = Q + (size_t)(b*SS + qrow) * H + h * HD + hi*8;
    bf16x8 qr0 = *(const bf16x8*)(qptr + 0);
    bf16x8 qr1 = *(const bf16x8*)(qptr + 16);
    bf16x8 qr2 = *(const bf16x8*)(qptr + 32);
    bf16x8 qr3 = *(const bf16x8*)(qptr + 48);
    bf16x8 qf[4];
    {
      const float sf = (float)qrow;
      #pragma unroll
      for (int e = 0; e < 8; e++){
        #pragma unroll
        for (int pr = 0; pr < 2; pr++){
          const int d = pr*16 + hi*8 + e;       // in [0,32)
          const float inv = exp2f(-0.4152410118609203f * (float)d);
          float rev = sf * inv * 0.15915494309189535f;
          rev -= floorf(rev);
          const float sn = __builtin_amdgcn_sinf(rev);
          const float cs = __builtin_amdgcn_cosf(rev);
          const float qa = bf2f((u16)(pr ? qr1[e] : qr0[e]));
          const float qb = bf2f((u16)(pr ? qr3[e] : qr2[e]));
          const u16 oa = f2bf((qa*cs - qb*sn) * QSC);
          const u16 ob = f2bf((qb*cs + qa*sn) * QSC);
          if (pr){ qf[1][e] = (short)oa; qf[3][e] = (short)ob; }
          else   { qf[0][e] = (short)oa; qf[2][e] = (short)ob; }
        }
      }
    }

    float mrun = -1e30f, lrun = 0.f;            // lrun = per-half partial sum
    f32x16 oacc[2] = {};
    uint4 vvA[2], vvB[2];

    // ---- prologue: stage tiles 0 and 1, drain, publish both ----
    stageK(0, 0); loadV(0, vvA);
    stageK(1, 1); loadV(1, vvB);
    asm volatile("s_waitcnt vmcnt(0)" ::: "memory");
    publishV(vvA, 0);
    publishV(vvB, 1);
    asm volatile("s_waitcnt lgkmcnt(0)" ::: "memory");
    __builtin_amdgcn_s_barrier();

    // compute one 64-wide KV tile (buffers = jt & 3)
    auto compute = [&](int jt){
      const int j0 = jt * 64;
      if (j0 > qw0) return;                     // wave fully masked in this tile
      const int kbuf = jt & 3;
      // ---- S^T = K . Q^T ----
      f32x16 sv[2] = {};
      __builtin_amdgcn_s_setprio(1);
      #pragma unroll
      for (int kb = 0; kb < 2; kb++){
        const int row = kb*32 + lq;
        #pragma unroll
        for (int c = 0; c < 4; c++){
          bf16x8 kf = *(const bf16x8*)&Ks[kbuf][row][(c*16 + hi*8) ^ ((row & 7) * 8)];
          sv[kb] = __builtin_amdgcn_mfma_f32_32x32x16_bf16(kf, qf[c], sv[kb], 0, 0, 0);
        }
      }
      __builtin_amdgcn_s_setprio(0);
      // ---- causal mask (diagonal-touching tiles only) ----
      if (j0 + 63 > qw0){
        #pragma unroll
        for (int kb = 0; kb < 2; kb++)
          #pragma unroll
          for (int r = 0; r < 16; r++){
            const int kg = j0 + kb*32 + (r & 3) + 8*(r >> 2) + 4*hi;
            if (kg > qrow) sv[kb][r] = -1e30f;
          }
      }
      // ---- online softmax (exp2 domain), tree reduce, partner lane l^32 ----
      float t16[16], t8[8], t4[4];
      #pragma unroll
      for (int r = 0; r < 16; r++) t16[r] = fmaxf(sv[0][r], sv[1][r]);
      #pragma unroll
      for (int r = 0; r < 8; r++) t8[r] = fmaxf(t16[r], t16[r+8]);
      #pragma unroll
      for (int r = 0; r < 4; r++) t4[r] = fmaxf(t8[r], t8[r+4]);
      float tm = fmaxf(fmaxf(t4[0], t4[2]), fmaxf(t4[1], t4[3]));
      tm = fmaxf(tm, __shfl_xor(tm, 32, 64));
      // defer-max: rescale only when new max exceeds old by > 11.5 (=8*log2e).
      if (__any(tm > mrun + 11.5f)){
        const float mn = fmaxf(mrun, tm);
        const float fac = exp2f(mrun - mn);
        mrun = mn;
        lrun *= fac;
        #pragma unroll
        for (int db = 0; db < 2; db++)
          #pragma unroll
          for (int r = 0; r < 16; r++) oacc[db][r] *= fac;
      }
      #pragma unroll
      for (int kb = 0; kb < 2; kb++)
        #pragma unroll
        for (int r = 0; r < 16; r++) sv[kb][r] = exp2f(sv[kb][r] - mrun);
      float s16[16], s8[8], s4[4];
      #pragma unroll
      for (int r = 0; r < 16; r++) s16[r] = sv[0][r] + sv[1][r];
      #pragma unroll
      for (int r = 0; r < 8; r++) s8[r] = s16[r] + s16[r+8];
      #pragma unroll
      for (int r = 0; r < 4; r++) s4[r] = s8[r] + s8[r+4];
      lrun += (s4[0] + s4[1]) + (s4[2] + s4[3]);   // per-half partial (shfl deferred)
      // ---- build PV B-frags: cvt_pk pairs, exchange halves via xor-32 ----
      u32x4 pw[4];
      #pragma unroll
      for (int kb = 0; kb < 2; kb++){
        #pragma unroll
        for (int half = 0; half < 2; half++){
          const int rb = half * 8;
          const u32 own0 = pk2(sv[kb][rb+0], sv[kb][rb+1]);
          const u32 own1 = pk2(sv[kb][rb+2], sv[kb][rb+3]);
          const u32 own2 = pk2(sv[kb][rb+4], sv[kb][rb+5]);
          const u32 own3 = pk2(sv[kb][rb+6], sv[kb][rb+7]);
          const u32 s0 = hi ? own0 : own2;
          const u32 s1 = hi ? own1 : own3;
          const u32 r0 = __shfl_xor(s0, 32, 64);
          const u32 r1 = __shfl_xor(s1, 32, 64);
          u32x4 pv;
          pv[0] = hi ? r0 : own0;
          pv[1] = hi ? r1 : own1;
          pv[2] = hi ? own2 : r0;
          pv[3] = hi ? own3 : r1;
          pw[kb*2 + half] = pv;
        }
      }
      // ---- O^T += V^T . P^T ----
      __builtin_amdgcn_s_setprio(1);
      #pragma unroll
      for (int db = 0; db < 2; db++){
        const int d = db*32 + lq;
        #pragma unroll
        for (int tt = 0; tt < 4; tt++){
          bf16x8 vf = *(const bf16x8*)&Vs[kbuf][d][(tt*16 + hi*8) ^ ((d >> 3) * 8)];
          bf16x8 pfr = __builtin_bit_cast(bf16x8, pw[tt]);
          oacc[db] = __builtin_amdgcn_mfma_f32_32x32x16_bf16(vf, pfr, oacc[db], 0, 0, 0);
        }
      }
      __builtin_amdgcn_s_setprio(0);
    };

    // ---- main loop: 2 tiles per pipeline step ----
    #pragma unroll 1
    for (int jt = 0; jt < NT; jt += 2){
      const bool more = (jt + 2 < NT);          // NT even: stages t+2 AND t+3
      if (more){
        stageK(jt + 2, (jt + 2) & 3); loadV(jt + 2, vvA);
        stageK(jt + 3, (jt + 3) & 3); loadV(jt + 3, vvB);
      }
      compute(jt);
      compute(jt + 1);
      if (more){
        asm volatile("s_waitcnt vmcnt(0)" ::: "memory");  // cover = 2 tiles of compute
        publishV(vvA, (jt + 2) & 3);
        publishV(vvB, (jt + 3) & 3);
      }
      asm volatile("s_waitcnt lgkmcnt(0)" ::: "memory");
      __builtin_amdgcn_s_barrier();
    }

    // ---- epilogue: combine deferred half-sums; lane owns q-row qrow ----
    lrun += __shfl_xor(lrun, 32, 64);
    const float rl = 1.0f / lrun;
    u16* op = O + (size_t)(b*SS + qrow) * H + h * HD;
    #pragma unroll
    for (int db = 0; db < 2; db++)
      #pragma unroll
      for (int rq = 0; rq < 4; rq++){
        ushort4 o4;
        o4.x = f2bf(oacc[db][rq*4 + 0] * rl);
        o4.y = f2bf(oacc[db][rq*4 + 1] * rl);
        o4.z = f2bf(oacc[db][rq*4 + 2] * rl);
        o4.w = f2bf(oacc[db][rq*4 + 3] * rl);
        *(ushort4*)(op + db*32 + rq*8 + 4*hi) = o4;
      }
  }
}

extern "C" void kernel_launch(void* const* d_in, const int* in_sizes, int n_in,
                              void* d_out, int out_size, void* d_ws, size_t ws_size,
                              hipStream_t stream){
  (void)in_sizes; (void)n_in; (void)out_size; (void)ws_size;
  const float* hs = (const float*)d_in[0];
  // d_in[1] = attention_mask (causal, implemented analytically)
  const float* wq = (const float*)d_in[2];
  const float* wk = (const float*)d_in[3];
  const float* wv = (const float*)d_in[4];
  const float* wo = (const float*)d_in[5];
  float* out = (float*)d_out;
  char* ws = (char*)d_ws;

  // workspace layout (bytes): Xb 16.8M | Wqt/Wkt/Wvt (contiguous, = flattened
  // Bt[6144][2048]) + Wot 4x8.4M | Vb 16.8M | Ob 16.8M  (~84MB)
  u16* Xb  = (u16*)ws;
  u16* Wqt = (u16*)(ws + (size_t)MM * H * 2);
  u16* Wkt = Wqt + (size_t)H * H;
  u16* Wvt = Wkt + (size_t)H * H;
  u16* Wot = Wvt + (size_t)H * H;
  u16* Vb  = Wot + (size_t)H * H;
  u16* Ob  = Vb  + (size_t)MM * H;
  // Q,K (bf16) live in d_out's 33.5MB until the final GEMM overwrites it
  u16* Qb  = (u16*)d_out;
  u16* Kb  = Qb + (size_t)MM * H;

  k_cvt<<<8192, 256, 0, stream>>>(hs, Xb);
  k_wtrans<<<dim3(64, 64, 4), dim3(32, 8), 0, stream>>>(wq, wk, wv, wo, Wqt, Wkt, Wvt, Wot);
  k_gemm8<<<1024, 512, 0, stream>>>(Xb, Wqt, Qb, Kb, Vb, MM, H);
  k_rope<<<2048, 256, 0, stream>>>(Kb);
  k_attn<<<dim3(8, 64), 256, 0, stream>>>(Qb, Kb, Vb, Ob);
  k_gemmo<<<512, 512, 0, stream>>>(Ob, Wot, out, MM, H, H);
}

// Round 17
// 272.749 us; speedup vs baseline: 1.0571x; 1.0571x over previous
//
#include <hip/hip_runtime.h>
#include <hip/hip_bf16.h>

#define H 2048
#define NH 32
#define HD 64
#define BB 2
#define SS 2048
#define MM (BB*SS)   // 4096 rows

typedef __attribute__((ext_vector_type(8))) short bf16x8;
typedef __attribute__((ext_vector_type(4))) float f32x4;
typedef __attribute__((ext_vector_type(16))) float f32x16;
typedef unsigned short u16;
typedef unsigned int u32;
typedef __attribute__((ext_vector_type(4))) u32 u32x4;

#define MFMA16(acc, av, bv) acc = __builtin_amdgcn_mfma_f32_16x16x32_bf16(av, bv, acc, 0, 0, 0)

static __device__ __forceinline__ u16 f2bf(float f){
  union { float f; u32 i; } v; v.f = f;
  u32 x = v.i;
  return (u16)((x + 0x7FFFu + ((x >> 16) & 1u)) >> 16);  // RNE
}
static __device__ __forceinline__ float bf2f(u16 u){
  union { u32 i; float f; } v; v.i = ((u32)u) << 16; return v.f;
}
// packed f32x2 -> bf16x2 (low = a, high = b), single HW instr
static __device__ __forceinline__ u32 pk2(float a, float b){
  u32 r;
  asm("v_cvt_pk_bf16_f32 %0, %1, %2" : "=v"(r) : "v"(a), "v"(b));
  return r;
}

static __device__ __forceinline__ void gload16(const u16* g, u16* l){
  __builtin_amdgcn_global_load_lds((const __attribute__((address_space(1))) void*)g,
                                   (__attribute__((address_space(3))) void*)l, 16, 0, 0);
}

// ---------------- 1. X f32 -> bf16 ----------------
__global__ void k_cvt(const float* __restrict__ src, u16* __restrict__ dst){
  const int i = (blockIdx.x * 256 + threadIdx.x) * 4;
  float4 v = *(const float4*)(src + i);
  ushort4 o;
  o.x = f2bf(v.x); o.y = f2bf(v.y); o.z = f2bf(v.z); o.w = f2bf(v.w);
  *(ushort4*)(dst + i) = o;
}

// ---------------- 2. W [K][N] f32 -> Wt [N][K] bf16 ----------------
__global__ void k_wtrans(const float* __restrict__ w0, const float* __restrict__ w1,
                         const float* __restrict__ w2, const float* __restrict__ w3,
                         u16* __restrict__ d0, u16* __restrict__ d1,
                         u16* __restrict__ d2, u16* __restrict__ d3){
  __shared__ float tile[32][33];
  const int z = blockIdx.z;
  const float* w = z==0 ? w0 : z==1 ? w1 : z==2 ? w2 : w3;
  u16* d        = z==0 ? d0 : z==1 ? d1 : z==2 ? d2 : d3;
  const int n0 = blockIdx.x * 32, k0 = blockIdx.y * 32;
  const int tx = threadIdx.x, ty = threadIdx.y;  // 32 x 8
  #pragma unroll
  for (int j = 0; j < 4; j++)
    tile[ty + 8*j][tx] = w[(size_t)(k0 + ty + 8*j) * H + n0 + tx];
  __syncthreads();
  #pragma unroll
  for (int j = 0; j < 4; j++)
    d[(size_t)(n0 + ty + 8*j) * H + k0 + tx] = f2bf(tile[tx][ty + 8*j]);
}

// ---------------- 3. QKV GEMM, flattened N=6144 (r13: 2 blocks/CU, banked best) ----------------
// BM=128 x BN=192 -> LDS 80 KiB -> 2 blocks/CU. Grid 32x32 = 1024 blocks.
// XCD swizzle: each XCD owns 4 gy n-panels (B-share 3MB L2-resident), streams A.
// r8 balanced 4-phase K-tile; counted vmcnt(5). Measured 109.5us, MfmaUtil 41%.
__global__ __launch_bounds__(512, 4) void k_gemm8(
    const u16* __restrict__ A, const u16* __restrict__ Bt,
    u16* __restrict__ CQ, u16* __restrict__ CK, u16* __restrict__ CV,
    int M, int K){
  __shared__ __align__(16) u16 As[2][128][64];
  __shared__ __align__(16) u16 Bs[2][192][64];
  const int flat = blockIdx.x;                  // 1024 blocks
  const int id = (flat & 7) * 128 + (flat >> 3);
  const int gy = id >> 5, gx = id & 31;         // 32 n-panels x 32 m-tiles
  const int m0 = gx * 128, n0 = gy * 192;
  const int t = threadIdx.x, w = t >> 6, l = t & 63;
  const int wm = w >> 2, wn = w & 3;            // wave rows wm*64.., cols wn*48..
  const int lrow = l & 15, lk = (l >> 4) * 8;
  const int sw = (lrow & 7) * 8;                // read-side swizzle
  const int sr = t >> 3, sc = (t & 7) * 8;      // staging lane pattern
  const int ssc = sc ^ ((sr & 7) * 8);          // pre-swizzled global col
  const int NK = K >> 6;

  auto stageA = [&](int kt, int u){
    const size_t kb = (size_t)kt * 64 + ssc;
    #pragma unroll
    for (int c = 0; c < 2; c++)
      gload16(A + (size_t)(m0 + c*64 + sr) * K + kb, &As[u][c*64 + sr][sc]);
  };
  auto stageB = [&](int kt, int u){
    const size_t kb = (size_t)kt * 64 + ssc;
    #pragma unroll
    for (int c = 0; c < 3; c++)
      gload16(Bt + (size_t)(n0 + c*64 + sr) * K + kb, &Bs[u][c*64 + sr][sc]);
  };

  f32x4 acc[4][3] = {};

  stageA(0, 0); stageB(0, 0);
  stageA(1, 1); stageB(1, 1);
  asm volatile("s_waitcnt vmcnt(5)" ::: "memory");
  __builtin_amdgcn_s_barrier();

  #pragma unroll 1
  for (int kt = 0; kt < NK; ++kt){
    const int u = kt & 1;
    const bool more = (kt + 2 < NK);
    bf16x8 b0[3], b1[3], a0, a1;

    // ---- phase 0: B kh0 + A mb{0,1} kh0 -> 6 MFMA ----
    #pragma unroll
    for (int n = 0; n < 3; n++)
      b0[n] = *(const bf16x8*)&Bs[u][wn*48 + n*16 + lrow][lk ^ sw];
    a0 = *(const bf16x8*)&As[u][wm*64 +  0 + lrow][lk ^ sw];
    a1 = *(const bf16x8*)&As[u][wm*64 + 16 + lrow][lk ^ sw];
    __builtin_amdgcn_s_setprio(1);
    #pragma unroll
    for (int n = 0; n < 3; n++){
      MFMA16(acc[0][n], a0, b0[n]);
      MFMA16(acc[1][n], a1, b0[n]);
    }
    __builtin_amdgcn_s_setprio(0);
    __builtin_amdgcn_s_barrier();

    // ---- phase 1: B kh1 + A mb{0,1} kh1 -> 6 MFMA  [B slot fully consumed] ----
    #pragma unroll
    for (int n = 0; n < 3; n++)
      b1[n] = *(const bf16x8*)&Bs[u][wn*48 + n*16 + lrow][(32 + lk) ^ sw];
    a0 = *(const bf16x8*)&As[u][wm*64 +  0 + lrow][(32 + lk) ^ sw];
    a1 = *(const bf16x8*)&As[u][wm*64 + 16 + lrow][(32 + lk) ^ sw];
    __builtin_amdgcn_s_setprio(1);
    #pragma unroll
    for (int n = 0; n < 3; n++){
      MFMA16(acc[0][n], a0, b1[n]);
      MFMA16(acc[1][n], a1, b1[n]);
    }
    __builtin_amdgcn_s_setprio(0);
    __builtin_amdgcn_s_barrier();

    // ---- phase 2: stage B(kt+2) into freed B slot; A mb{2,3} kh0 -> 6 MFMA ----
    if (more) stageB(kt + 2, u);
    a0 = *(const bf16x8*)&As[u][wm*64 + 32 + lrow][lk ^ sw];
    a1 = *(const bf16x8*)&As[u][wm*64 + 48 + lrow][lk ^ sw];
    __builtin_amdgcn_s_setprio(1);
    #pragma unroll
    for (int n = 0; n < 3; n++){
      MFMA16(acc[2][n], a0, b0[n]);
      MFMA16(acc[3][n], a1, b0[n]);
    }
    __builtin_amdgcn_s_setprio(0);
    __builtin_amdgcn_s_barrier();

    // ---- phase 3: A mb{2,3} kh1 -> 6 MFMA ----
    a0 = *(const bf16x8*)&As[u][wm*64 + 32 + lrow][(32 + lk) ^ sw];
    a1 = *(const bf16x8*)&As[u][wm*64 + 48 + lrow][(32 + lk) ^ sw];
    __builtin_amdgcn_s_setprio(1);
    #pragma unroll
    for (int n = 0; n < 3; n++){
      MFMA16(acc[2][n], a0, b1[n]);
      MFMA16(acc[3][n], a1, b1[n]);
    }
    __builtin_amdgcn_s_setprio(0);
    __builtin_amdgcn_s_barrier();   // A slot fully consumed

    if (more){
      stageA(kt + 2, u);
      asm volatile("s_waitcnt vmcnt(5)" ::: "memory");   // kt+1 landed; kt+2's 5 in flight
      __builtin_amdgcn_s_barrier();
    } else if (kt + 1 < NK){
      asm volatile("s_waitcnt vmcnt(0)" ::: "memory");
      __builtin_amdgcn_s_barrier();
    }
  }

  #pragma unroll
  for (int m = 0; m < 4; m++)
    #pragma unroll
    for (int n = 0; n < 3; n++){
      const int ncol = n0 + wn*48 + n*16 + lrow;
      const int z = ncol >> 11;
      u16* C = (z == 0 ? CQ : z == 1 ? CK : CV) + (ncol & 2047);
      #pragma unroll
      for (int r = 0; r < 4; r++){
        const int row = m0 + wm*64 + m*16 + (l >> 4)*4 + r;
        C[(size_t)row * H] = f2bf(acc[m][n][r]);
      }
    }
}

// ---------------- 3b. out-proj GEMM: C[4096][2048] f32 = A * Wot^T ----------------
// BM=128 x BN=128 -> LDS 64 KiB -> 2 blocks/CU. Grid 32x16 = 512 blocks.
__global__ __launch_bounds__(512, 4) void k_gemmo(
    const u16* __restrict__ A, const u16* __restrict__ Bt,
    float* __restrict__ C, int M, int N, int K){
  __shared__ __align__(16) u16 As[2][128][64];
  __shared__ __align__(16) u16 Bs[2][128][64];
  const int flat = blockIdx.x;                 // 512 blocks
  const int id = (flat & 7) * 64 + (flat >> 3);
  const int gy = id >> 5, gx = id & 31;        // 16 n-panels x 32 m-tiles
  const int m0 = gx * 128, n0 = gy * 128;
  const int t = threadIdx.x, w = t >> 6, l = t & 63;
  const int wm = w >> 2, wn = w & 3;           // wave rows wm*64.., cols wn*32..
  const int lrow = l & 15, lk = (l >> 4) * 8;
  const int sw = (lrow & 7) * 8;
  const int sr = t >> 3, sc = (t & 7) * 8;
  const int ssc = sc ^ ((sr & 7) * 8);
  const int NK = K >> 6;

  auto stageA = [&](int kt, int u){
    const size_t kb = (size_t)kt * 64 + ssc;
    #pragma unroll
    for (int c = 0; c < 2; c++)
      gload16(A + (size_t)(m0 + c*64 + sr) * K + kb, &As[u][c*64 + sr][sc]);
  };
  auto stageB = [&](int kt, int u){
    const size_t kb = (size_t)kt * 64 + ssc;
    #pragma unroll
    for (int c = 0; c < 2; c++)
      gload16(Bt + (size_t)(n0 + c*64 + sr) * K + kb, &Bs[u][c*64 + sr][sc]);
  };

  f32x4 acc[4][2] = {};

  stageA(0, 0); stageB(0, 0);
  stageA(1, 1); stageB(1, 1);
  asm volatile("s_waitcnt vmcnt(4)" ::: "memory");
  __builtin_amdgcn_s_barrier();

  #pragma unroll 1
  for (int kt = 0; kt < NK; ++kt){
    const int u = kt & 1;
    const bool more = (kt + 2 < NK);
    bf16x8 b0[2], b1[2], a0, a1;

    // p0: B kh0 + A mb{0,1} kh0 -> 4 MFMA
    #pragma unroll
    for (int n = 0; n < 2; n++)
      b0[n] = *(const bf16x8*)&Bs[u][wn*32 + n*16 + lrow][lk ^ sw];
    a0 = *(const bf16x8*)&As[u][wm*64 +  0 + lrow][lk ^ sw];
    a1 = *(const bf16x8*)&As[u][wm*64 + 16 + lrow][lk ^ sw];
    __builtin_amdgcn_s_setprio(1);
    #pragma unroll
    for (int n = 0; n < 2; n++){
      MFMA16(acc[0][n], a0, b0[n]);
      MFMA16(acc[1][n], a1, b0[n]);
    }
    __builtin_amdgcn_s_setprio(0);
    __builtin_amdgcn_s_barrier();

    // p1: B kh1 + A mb{0,1} kh1 -> 4 MFMA  [B slot consumed]
    #pragma unroll
    for (int n = 0; n < 2; n++)
      b1[n] = *(const bf16x8*)&Bs[u][wn*32 + n*16 + lrow][(32 + lk) ^ sw];
    a0 = *(const bf16x8*)&As[u][wm*64 +  0 + lrow][(32 + lk) ^ sw];
    a1 = *(const bf16x8*)&As[u][wm*64 + 16 + lrow][(32 + lk) ^ sw];
    __builtin_amdgcn_s_setprio(1);
    #pragma unroll
    for (int n = 0; n < 2; n++){
      MFMA16(acc[0][n], a0, b1[n]);
      MFMA16(acc[1][n], a1, b1[n]);
    }
    __builtin_amdgcn_s_setprio(0);
    __builtin_amdgcn_s_barrier();

    // p2: stage B(kt+2); A mb{2,3} kh0 -> 4 MFMA
    if (more) stageB(kt + 2, u);
    a0 = *(const bf16x8*)&As[u][wm*64 + 32 + lrow][lk ^ sw];
    a1 = *(const bf16x8*)&As[u][wm*64 + 48 + lrow][lk ^ sw];
    __builtin_amdgcn_s_setprio(1);
    #pragma unroll
    for (int n = 0; n < 2; n++){
      MFMA16(acc[2][n], a0, b0[n]);
      MFMA16(acc[3][n], a1, b0[n]);
    }
    __builtin_amdgcn_s_setprio(0);
    __builtin_amdgcn_s_barrier();

    // p3: A mb{2,3} kh1 -> 4 MFMA
    a0 = *(const bf16x8*)&As[u][wm*64 + 32 + lrow][(32 + lk) ^ sw];
    a1 = *(const bf16x8*)&As[u][wm*64 + 48 + lrow][(32 + lk) ^ sw];
    __builtin_amdgcn_s_setprio(1);
    #pragma unroll
    for (int n = 0; n < 2; n++){
      MFMA16(acc[2][n], a0, b1[n]);
      MFMA16(acc[3][n], a1, b1[n]);
    }
    __builtin_amdgcn_s_setprio(0);
    __builtin_amdgcn_s_barrier();

    if (more){
      stageA(kt + 2, u);
      asm volatile("s_waitcnt vmcnt(4)" ::: "memory");
      __builtin_amdgcn_s_barrier();
    } else if (kt + 1 < NK){
      asm volatile("s_waitcnt vmcnt(0)" ::: "memory");
      __builtin_amdgcn_s_barrier();
    }
  }

  #pragma unroll
  for (int m = 0; m < 4; m++)
    #pragma unroll
    for (int n = 0; n < 2; n++){
      const int col = n0 + wn*32 + n*16 + lrow;
      #pragma unroll
      for (int r = 0; r < 4; r++){
        const int row = m0 + wm*64 + m*16 + (l >> 4)*4 + r;
        C[(size_t)row * N + col] = acc[m][n][r];
      }
    }
}

// ---------------- 4. RoPE on K only, in place (Q-RoPE fused into k_attn) ----------------
__global__ void k_rope(u16* __restrict__ Kp){
  const int idx = blockIdx.x * 256 + threadIdx.x;  // 4096*32*4 threads
  const int quad = idx & 3;
  const int h = (idx >> 2) & 31;
  const int row = idx >> 7;
  const int s = row & (SS - 1);
  const int i0 = quad * 8;
  u16* k = Kp + (size_t)row * H + h * HD;
  uint4 k1v = *(const uint4*)(k + i0);
  uint4 k2v = *(const uint4*)(k + i0 + 32);
  u16* k1 = (u16*)&k1v; u16* k2 = (u16*)&k2v;
  const float sf = (float)s;
  #pragma unroll
  for (int e = 0; e < 8; e++){
    const int i = i0 + e;
    const float inv = exp2f(-0.4152410118609203f * (float)i);  // 10000^(-i/32)
    float rev = sf * inv * 0.15915494309189535f;               // radians -> revolutions
    rev -= floorf(rev);
    const float sn = __builtin_amdgcn_sinf(rev);
    const float cs = __builtin_amdgcn_cosf(rev);
    const float ka = bf2f(k1[e]), kb = bf2f(k2[e]);
    k1[e] = f2bf(ka*cs - kb*sn);
    k2[e] = f2bf(kb*cs + ka*sn);
  }
  *(uint4*)(k + i0)      = k1v;
  *(uint4*)(k + i0 + 32) = k2v;
}

// ---------------- 5. causal flash attention (r14 version, measured best) ----------------
// block = 256 thr (4 waves x 32 q-rows), grid 8x64 = 512 blocks (2/CU).
// Block x handles q-tiles {15-x, x} -> uniform 36 KV-iterations.
// 2-tile unrolled pipeline: Ks[4]/Vs[4]; per 2 tiles: stage t+2,t+3, compute
// both, one vmcnt(0)+publish+barrier. + defer-max (THR=11.5 exp2-domain)
// + deferred sum-shfl.
__global__ __launch_bounds__(256, 2) void k_attn(
    const u16* __restrict__ Q, const u16* __restrict__ K,
    const u16* __restrict__ V, u16* __restrict__ O){
  __shared__ __align__(16) u16 Ks[4][64][64];   // swizzled: col ^ (row&7)*8
  __shared__ __align__(16) u16 Vs[4][64][72];   // transposed Vs[d][j], j ^ (d>>3)*8
  const int t = threadIdx.x, w = t >> 6, l = t & 63;
  const int x = blockIdx.x, bh = blockIdx.y;
  const int b = bh >> 5, h = bh & 31;
  const u16* kp = K + (size_t)(b*SS) * H + h * HD;
  const u16* vp = V + (size_t)(b*SS) * H + h * HD;
  const int sr = t >> 3, sc = (t & 7) * 8;      // staging: linear-LDS pattern
  const int ssc = sc ^ ((sr & 7) * 8);          // pre-swizzled global col for K
  const int hi = l >> 5, lq = l & 31;
  const float QSC = 0.18033688011112042f;       // (1/8) * log2(e)

  auto stageK = [&](int tile, int buf){
    const int jb = tile * 64;
    gload16(kp + (size_t)(jb + sr) * H + ssc,      &Ks[buf][sr][sc]);
    gload16(kp + (size_t)(jb + 32 + sr) * H + ssc, &Ks[buf][32 + sr][sc]);
  };
  auto loadV = [&](int tile, uint4* vv){
    const int jb = tile * 64;
    vv[0] = *(const uint4*)(vp + (size_t)(jb + sr) * H + sc);
    vv[1] = *(const uint4*)(vp + (size_t)(jb + 32 + sr) * H + sc);
  };
  auto publishV = [&](const uint4* vv, int buf){
    #pragma unroll
    for (int c = 0; c < 2; c++){
      const int j = c*32 + sr;
      const u16* pv = (const u16*)&vv[c];
      #pragma unroll
      for (int e = 0; e < 8; e++){
        const int d = sc + e;
        Vs[buf][d][j ^ ((d >> 3) * 8)] = pv[e];
      }
    }
  };

  #pragma unroll 1
  for (int pp = 0; pp < 2; pp++){
    const int qt = pp ? x : (15 - x);           // heavy pass first
    const int NT = 2*qt + 2;                    // even
    const int qw0 = qt*128 + w*32;
    const int qrow = qw0 + lq;                  // this lane's q index (= seq pos)

    // ---- Q fragments: load raw, apply RoPE + QSC in-register ----
    const u16* qptr = Q + (size_t)(b*SS + qrow) * H + h * HD + hi*8;
    bf16x8 qr0 = *(const bf16x8*)(qptr + 0);
    bf16x8 qr1 = *(const bf16x8*)(qptr + 16);
    bf16x8 qr2 = *(const bf16x8*)(qptr + 32);
    bf16x8 qr3 = *(const bf16x8*)(qptr + 48);
    bf16x8 qf[4];
    {
      const float sf = (float)qrow;
      #pragma unroll
      for (int e = 0; e < 8; e++){
        #pragma unroll
        for (int pr = 0; pr < 2; pr++){
          const int d = pr*16 + hi*8 + e;       // in [0,32)
          const float inv = exp2f(-0.4152410118609203f * (float)d);
          float rev = sf * inv * 0.15915494309189535f;
          rev -= floorf(rev);
          const float sn = __builtin_amdgcn_sinf(rev);
          const float cs = __builtin_amdgcn_cosf(rev);
          const float qa = bf2f((u16)(pr ? qr1[e] : qr0[e]));
          const float qb = bf2f((u16)(pr ? qr3[e] : qr2[e]));
          const u16 oa = f2bf((qa*cs - qb*sn) * QSC);
          const u16 ob = f2bf((qb*cs + qa*sn) * QSC);
          if (pr){ qf[1][e] = (short)oa; qf[3][e] = (short)ob; }
          else   { qf[0][e] = (short)oa; qf[2][e] = (short)ob; }
        }
      }
    }

    float mrun = -1e30f, lrun = 0.f;            // lrun = per-half partial sum
    f32x16 oacc[2] = {};
    uint4 vvA[2], vvB[2];

    // ---- prologue: stage tiles 0 and 1, drain, publish both ----
    stageK(0, 0); loadV(0, vvA);
    stageK(1, 1); loadV(1, vvB);
    asm volatile("s_waitcnt vmcnt(0)" ::: "memory");
    publishV(vvA, 0);
    publishV(vvB, 1);
    asm volatile("s_waitcnt lgkmcnt(0)" ::: "memory");
    __builtin_amdgcn_s_barrier();

    // compute one 64-wide KV tile (buffers = jt & 3)
    auto compute = [&](int jt){
      const int j0 = jt * 64;
      if (j0 > qw0) return;                     // wave fully masked in this tile
      const int kbuf = jt & 3;
      // ---- S^T = K . Q^T ----
      f32x16 sv[2] = {};
      __builtin_amdgcn_s_setprio(1);
      #pragma unroll
      for (int kb = 0; kb < 2; kb++){
        const int row = kb*32 + lq;
        #pragma unroll
        for (int c = 0; c < 4; c++){
          bf16x8 kf = *(const bf16x8*)&Ks[kbuf][row][(c*16 + hi*8) ^ ((row & 7) * 8)];
          sv[kb] = __builtin_amdgcn_mfma_f32_32x32x16_bf16(kf, qf[c], sv[kb], 0, 0, 0);
        }
      }
      __builtin_amdgcn_s_setprio(0);
      // ---- causal mask (diagonal-touching tiles only) ----
      if (j0 + 63 > qw0){
        #pragma unroll
        for (int kb = 0; kb < 2; kb++)
          #pragma unroll
          for (int r = 0; r < 16; r++){
            const int kg = j0 + kb*32 + (r & 3) + 8*(r >> 2) + 4*hi;
            if (kg > qrow) sv[kb][r] = -1e30f;
          }
      }
      // ---- online softmax (exp2 domain), tree reduce, partner lane l^32 ----
      float t16[16], t8[8], t4[4];
      #pragma unroll
      for (int r = 0; r < 16; r++) t16[r] = fmaxf(sv[0][r], sv[1][r]);
      #pragma unroll
      for (int r = 0; r < 8; r++) t8[r] = fmaxf(t16[r], t16[r+8]);
      #pragma unroll
      for (int r = 0; r < 4; r++) t4[r] = fmaxf(t8[r], t8[r+4]);
      float tm = fmaxf(fmaxf(t4[0], t4[2]), fmaxf(t4[1], t4[3]));
      tm = fmaxf(tm, __shfl_xor(tm, 32, 64));
      // defer-max: rescale only when new max exceeds old by > 11.5 (=8*log2e).
      if (__any(tm > mrun + 11.5f)){
        const float mn = fmaxf(mrun, tm);
        const float fac = exp2f(mrun - mn);
        mrun = mn;
        lrun *= fac;
        #pragma unroll
        for (int db = 0; db < 2; db++)
          #pragma unroll
          for (int r = 0; r < 16; r++) oacc[db][r] *= fac;
      }
      #pragma unroll
      for (int kb = 0; kb < 2; kb++)
        #pragma unroll
        for (int r = 0; r < 16; r++) sv[kb][r] = exp2f(sv[kb][r] - mrun);
      float s16[16], s8[8], s4[4];
      #pragma unroll
      for (int r = 0; r < 16; r++) s16[r] = sv[0][r] + sv[1][r];
      #pragma unroll
      for (int r = 0; r < 8; r++) s8[r] = s16[r] + s16[r+8];
      #pragma unroll
      for (int r = 0; r < 4; r++) s4[r] = s8[r] + s8[r+4];
      lrun += (s4[0] + s4[1]) + (s4[2] + s4[3]);   // per-half partial (shfl deferred)
      // ---- build PV B-frags: cvt_pk pairs, exchange halves via xor-32 ----
      u32x4 pw[4];
      #pragma unroll
      for (int kb = 0; kb < 2; kb++){
        #pragma unroll
        for (int half = 0; half < 2; half++){
          const int rb = half * 8;
          const u32 own0 = pk2(sv[kb][rb+0], sv[kb][rb+1]);
          const u32 own1 = pk2(sv[kb][rb+2], sv[kb][rb+3]);
          const u32 own2 = pk2(sv[kb][rb+4], sv[kb][rb+5]);
          const u32 own3 = pk2(sv[kb][rb+6], sv[kb][rb+7]);
          const u32 s0 = hi ? own0 : own2;
          const u32 s1 = hi ? own1 : own3;
          const u32 r0 = __shfl_xor(s0, 32, 64);
          const u32 r1 = __shfl_xor(s1, 32, 64);
          u32x4 pv;
          pv[0] = hi ? r0 : own0;
          pv[1] = hi ? r1 : own1;
          pv[2] = hi ? own2 : r0;
          pv[3] = hi ? own3 : r1;
          pw[kb*2 + half] = pv;
        }
      }
      // ---- O^T += V^T . P^T ----
      __builtin_amdgcn_s_setprio(1);
      #pragma unroll
      for (int db = 0; db < 2; db++){
        const int d = db*32 + lq;
        #pragma unroll
        for (int tt = 0; tt < 4; tt++){
          bf16x8 vf = *(const bf16x8*)&Vs[kbuf][d][(tt*16 + hi*8) ^ ((d >> 3) * 8)];
          bf16x8 pfr = __builtin_bit_cast(bf16x8, pw[tt]);
          oacc[db] = __builtin_amdgcn_mfma_f32_32x32x16_bf16(vf, pfr, oacc[db], 0, 0, 0);
        }
      }
      __builtin_amdgcn_s_setprio(0);
    };

    // ---- main loop: 2 tiles per pipeline step ----
    #pragma unroll 1
    for (int jt = 0; jt < NT; jt += 2){
      const bool more = (jt + 2 < NT);          // NT even: stages t+2 AND t+3
      if (more){
        stageK(jt + 2, (jt + 2) & 3); loadV(jt + 2, vvA);
        stageK(jt + 3, (jt + 3) & 3); loadV(jt + 3, vvB);
      }
      compute(jt);
      compute(jt + 1);
      if (more){
        asm volatile("s_waitcnt vmcnt(0)" ::: "memory");  // cover = 2 tiles of compute
        publishV(vvA, (jt + 2) & 3);
        publishV(vvB, (jt + 3) & 3);
      }
      asm volatile("s_waitcnt lgkmcnt(0)" ::: "memory");
      __builtin_amdgcn_s_barrier();
    }

    // ---- epilogue: combine deferred half-sums; lane owns q-row qrow ----
    lrun += __shfl_xor(lrun, 32, 64);
    const float rl = 1.0f / lrun;
    u16* op = O + (size_t)(b*SS + qrow) * H + h * HD;
    #pragma unroll
    for (int db = 0; db < 2; db++)
      #pragma unroll
      for (int rq = 0; rq < 4; rq++){
        ushort4 o4;
        o4.x = f2bf(oacc[db][rq*4 + 0] * rl);
        o4.y = f2bf(oacc[db][rq*4 + 1] * rl);
        o4.z = f2bf(oacc[db][rq*4 + 2] * rl);
        o4.w = f2bf(oacc[db][rq*4 + 3] * rl);
        *(ushort4*)(op + db*32 + rq*8 + 4*hi) = o4;
      }
  }
}

extern "C" void kernel_launch(void* const* d_in, const int* in_sizes, int n_in,
                              void* d_out, int out_size, void* d_ws, size_t ws_size,
                              hipStream_t stream){
  (void)in_sizes; (void)n_in; (void)out_size; (void)ws_size;
  const float* hs = (const float*)d_in[0];
  // d_in[1] = attention_mask (causal, implemented analytically)
  const float* wq = (const float*)d_in[2];
  const float* wk = (const float*)d_in[3];
  const float* wv = (const float*)d_in[4];
  const float* wo = (const float*)d_in[5];
  float* out = (float*)d_out;
  char* ws = (char*)d_ws;

  // workspace layout (bytes): Xb 16.8M | Wqt/Wkt/Wvt (contiguous, = flattened
  // Bt[6144][2048]) + Wot 4x8.4M | Vb 16.8M | Ob 16.8M  (~84MB)
  u16* Xb  = (u16*)ws;
  u16* Wqt = (u16*)(ws + (size_t)MM * H * 2);
  u16* Wkt = Wqt + (size_t)H * H;
  u16* Wvt = Wkt + (size_t)H * H;
  u16* Wot = Wvt + (size_t)H * H;
  u16* Vb  = Wot + (size_t)H * H;
  u16* Ob  = Vb  + (size_t)MM * H;
  // Q,K (bf16) live in d_out's 33.5MB until the final GEMM overwrites it
  u16* Qb  = (u16*)d_out;
  u16* Kb  = Qb + (size_t)MM * H;

  k_cvt<<<8192, 256, 0, stream>>>(hs, Xb);
  k_wtrans<<<dim3(64, 64, 4), dim3(32, 8), 0, stream>>>(wq, wk, wv, wo, Wqt, Wkt, Wvt, Wot);
  k_gemm8<<<1024, 512, 0, stream>>>(Xb, Wqt, Qb, Kb, Vb, MM, H);
  k_rope<<<2048, 256, 0, stream>>>(Kb);
  k_attn<<<dim3(8, 64), 256, 0, stream>>>(Qb, Kb, Vb, Ob);
  k_gemmo<<<512, 512, 0, stream>>>(Ob, Wot, out, MM, H, H);
}